// Round 1
// baseline (1712.890 us; speedup 1.0000x reference)
//
#include <hip/hip_runtime.h>
#include <hip/hip_bf16.h>

#define H 19
#define Bv 2
#define Sv 2048
#define Dv 1024
#define DHv 64

#define QSZ (Bv*H*Sv*DHv)   // 4,980,736 floats
#define BIAS_OFF 0
#define Q_OFF 4096

// ---------------- bias: relu(coords@wb1+bb1)@wb2+bb2 -> [H,DH] ----------------
__global__ void bias_kernel(const float* __restrict__ coords,
                            const float* __restrict__ wb1,
                            const float* __restrict__ bb1,
                            const float* __restrict__ wb2,
                            const float* __restrict__ bb2,
                            float* __restrict__ bias) {
    int h = blockIdx.x;
    int e = threadIdx.x;
    float c0 = coords[h*2 + 0];
    float c1 = coords[h*2 + 1];
    float acc = bb2[e];
    for (int d = 0; d < Dv; ++d) {
        float hd = c0*wb1[d] + c1*wb1[Dv + d] + bb1[d];
        hd = fmaxf(hd, 0.0f);
        acc += hd * wb2[d*DHv + e];
    }
    bias[h*DHv + e] = acc;
}

// ---------------- QKV projection: per (mtile, head, type) 64x64 tile ----------------
// X [B*S, D] @ W[h] [D, DH] (+bias for q) -> q/k/v [B,H,S,DH]
__global__ __launch_bounds__(256) void qkv_gemm(const float* __restrict__ x,
                                                const float* __restrict__ wq,
                                                const float* __restrict__ wk,
                                                const float* __restrict__ wv,
                                                const float* __restrict__ bias,
                                                float* __restrict__ qbase) {
    const int mt = blockIdx.x;
    const int h  = blockIdx.y;
    const int t  = blockIdx.z;
    const float* w = (t == 0) ? wq : (t == 1) ? wk : wv;
    w += (size_t)h * Dv * DHv;
    float* outp = qbase + (size_t)t * QSZ;

    __shared__ float As[16][68];   // As[k_local][m_local]  (transposed for b128 reads)
    __shared__ float Bs[16][68];   // Bs[k_local][n_local]

    const int tx = threadIdx.x, ty = threadIdx.y;
    const int tid = ty*16 + tx;
    const int m0 = mt*64;

    const int arow = tid >> 2, acol4 = tid & 3;     // A: 64 rows x 4 float4 of k
    const int brow = tid >> 4, bcol4 = tid & 15;    // B: 16 rows x 16 float4 of n

    float acc[4][4] = {};

    for (int kt = 0; kt < Dv; kt += 16) {
        float4 av = *(const float4*)&x[(size_t)(m0 + arow)*Dv + kt + 4*acol4];
        float4 bv = *(const float4*)&w[(size_t)(kt + brow)*DHv + 4*bcol4];
        __syncthreads();
        As[4*acol4 + 0][arow] = av.x;
        As[4*acol4 + 1][arow] = av.y;
        As[4*acol4 + 2][arow] = av.z;
        As[4*acol4 + 3][arow] = av.w;
        *(float4*)&Bs[brow][4*bcol4] = bv;
        __syncthreads();
        #pragma unroll
        for (int kk = 0; kk < 16; ++kk) {
            float4 a = *(const float4*)&As[kk][ty*4];
            float4 b = *(const float4*)&Bs[kk][tx*4];
            acc[0][0] += a.x*b.x; acc[0][1] += a.x*b.y; acc[0][2] += a.x*b.z; acc[0][3] += a.x*b.w;
            acc[1][0] += a.y*b.x; acc[1][1] += a.y*b.y; acc[1][2] += a.y*b.z; acc[1][3] += a.y*b.w;
            acc[2][0] += a.z*b.x; acc[2][1] += a.z*b.y; acc[2][2] += a.z*b.z; acc[2][3] += a.z*b.w;
            acc[3][0] += a.w*b.x; acc[3][1] += a.w*b.y; acc[3][2] += a.w*b.z; acc[3][3] += a.w*b.w;
        }
    }

    float4 bvq = make_float4(0.f, 0.f, 0.f, 0.f);
    if (t == 0) bvq = *(const float4*)&bias[h*DHv + tx*4];

    #pragma unroll
    for (int i = 0; i < 4; ++i) {
        int grow = m0 + ty*4 + i;
        int bb = grow >> 11;          // /2048
        int ss = grow & 2047;
        float4 o;
        o.x = acc[i][0] + bvq.x;
        o.y = acc[i][1] + bvq.y;
        o.z = acc[i][2] + bvq.z;
        o.w = acc[i][3] + bvq.w;
        *(float4*)&outp[(((size_t)bb*H + h)*Sv + ss)*DHv + tx*4] = o;
    }
}

// ---------------- flash attention: per (qtile, head, batch) ----------------
__global__ __launch_bounds__(256) void attn_kernel(const float* __restrict__ q,
                                                   const float* __restrict__ k,
                                                   const float* __restrict__ v,
                                                   float* __restrict__ heads) {
    const int qt = blockIdx.x;
    const int h  = blockIdx.y;
    const int b  = blockIdx.z;

    __shared__ float Qs[64][68];
    __shared__ float KPs[64][68];   // K tile; reused as P tile after scores
    __shared__ float Vs[64][68];

    const int tx = threadIdx.x, ty = threadIdx.y;
    const int tid = ty*16 + tx;
    const float scale = 0.125f;  // 1/sqrt(64)

    const float* qb = q + (((size_t)b*H + h)*Sv + qt*64)*DHv;
    const float* kb = k + (((size_t)b*H + h)*Sv)*DHv;
    const float* vb = v + (((size_t)b*H + h)*Sv)*DHv;

    #pragma unroll
    for (int i = 0; i < 4; ++i) {
        int f = tid + i*256;
        int r = f >> 4, c4 = f & 15;
        *(float4*)&Qs[r][c4*4] = *(const float4*)&qb[r*DHv + c4*4];
    }

    float m_i[4], l_i[4], ov[4][4];
    #pragma unroll
    for (int i = 0; i < 4; ++i) {
        m_i[i] = -1e30f; l_i[i] = 0.f;
        ov[i][0] = ov[i][1] = ov[i][2] = ov[i][3] = 0.f;
    }

    for (int jt = 0; jt < Sv/64; ++jt) {
        __syncthreads();   // previous PV reads of KPs/Vs complete
        #pragma unroll
        for (int i = 0; i < 4; ++i) {
            int f = tid + i*256;
            int r = f >> 4, c4 = f & 15;
            *(float4*)&KPs[r][c4*4] = *(const float4*)&kb[(size_t)(jt*64 + r)*DHv + c4*4];
            *(float4*)&Vs[r][c4*4]  = *(const float4*)&vb[(size_t)(jt*64 + r)*DHv + c4*4];
        }
        __syncthreads();

        // scores: sc[i][j] = Q[ty*4+i] . K[tx*4+j]
        float sc[4][4] = {};
        #pragma unroll
        for (int e4 = 0; e4 < 16; ++e4) {
            float4 qv[4], kv[4];
            #pragma unroll
            for (int i = 0; i < 4; ++i) qv[i] = *(const float4*)&Qs[ty*4 + i][e4*4];
            #pragma unroll
            for (int j = 0; j < 4; ++j) kv[j] = *(const float4*)&KPs[tx*4 + j][e4*4];
            #pragma unroll
            for (int i = 0; i < 4; ++i)
                #pragma unroll
                for (int j = 0; j < 4; ++j)
                    sc[i][j] += qv[i].x*kv[j].x + qv[i].y*kv[j].y + qv[i].z*kv[j].z + qv[i].w*kv[j].w;
        }

        // online softmax (rows = ty*4+i, reduce across 16 tx lanes)
        float p[4][4];
        #pragma unroll
        for (int i = 0; i < 4; ++i) {
            float mx = fmaxf(fmaxf(sc[i][0], sc[i][1]), fmaxf(sc[i][2], sc[i][3])) * scale;
            #pragma unroll
            for (int off = 1; off < 16; off <<= 1) mx = fmaxf(mx, __shfl_xor(mx, off));
            float m_new = fmaxf(m_i[i], mx);
            float corr = __expf(m_i[i] - m_new);
            float lsum = 0.f;
            #pragma unroll
            for (int j = 0; j < 4; ++j) {
                p[i][j] = __expf(sc[i][j]*scale - m_new);
                lsum += p[i][j];
            }
            #pragma unroll
            for (int off = 1; off < 16; off <<= 1) lsum += __shfl_xor(lsum, off);
            l_i[i] = l_i[i]*corr + lsum;
            m_i[i] = m_new;
            ov[i][0] *= corr; ov[i][1] *= corr; ov[i][2] *= corr; ov[i][3] *= corr;
        }
        __syncthreads();   // all score reads of KPs done
        #pragma unroll
        for (int i = 0; i < 4; ++i)
            *(float4*)&KPs[ty*4 + i][tx*4] = make_float4(p[i][0], p[i][1], p[i][2], p[i][3]);
        __syncthreads();   // P visible

        // PV: ov[i][:] += sum_c P[ty*4+i][c] * V[c][tx*4..+3]
        #pragma unroll
        for (int c4 = 0; c4 < 16; ++c4) {
            float4 pv[4];
            #pragma unroll
            for (int i = 0; i < 4; ++i) pv[i] = *(const float4*)&KPs[ty*4 + i][c4*4];
            #pragma unroll
            for (int cc = 0; cc < 4; ++cc) {
                float4 vv = *(const float4*)&Vs[c4*4 + cc][tx*4];
                #pragma unroll
                for (int i = 0; i < 4; ++i) {
                    float pp = (cc == 0) ? pv[i].x : (cc == 1) ? pv[i].y : (cc == 2) ? pv[i].z : pv[i].w;
                    ov[i][0] += pp*vv.x; ov[i][1] += pp*vv.y; ov[i][2] += pp*vv.z; ov[i][3] += pp*vv.w;
                }
            }
        }
    }

    #pragma unroll
    for (int i = 0; i < 4; ++i) {
        float inv = 1.0f / l_i[i];
        int r = qt*64 + ty*4 + i;
        float4 o = make_float4(ov[i][0]*inv, ov[i][1]*inv, ov[i][2]*inv, ov[i][3]*inv);
        *(float4*)&heads[(((size_t)b*H + h)*Sv + r)*DHv + tx*4] = o;
    }
}

// ---------------- GNN mix + concat: per (b,s) ----------------
__global__ __launch_bounds__(256) void mix_kernel(const float* __restrict__ heads,
                                                  const float* __restrict__ w_mix,
                                                  const float* __restrict__ adj,
                                                  float* __restrict__ concat) {
    const int bs = blockIdx.x;
    const int b = bs >> 11, s = bs & 2047;
    __shared__ float Mh[H*DHv];
    __shared__ float Msg[H*DHv];
    __shared__ float Wm[DHv*DHv];
    __shared__ float Adj[H*H];
    const int tid = threadIdx.x;

    for (int i = tid; i < DHv*DHv; i += 256) Wm[i] = w_mix[i];
    for (int i = tid; i < H*H; i += 256) Adj[i] = adj[i];
    for (int i = tid; i < H*DHv; i += 256) {
        int hh = i >> 6, e = i & 63;
        Mh[i] = heads[(((size_t)b*H + hh)*Sv + s)*DHv + e];
    }
    __syncthreads();
    for (int i = tid; i < H*DHv; i += 256) {
        int hh = i >> 6, e = i & 63;
        float acc = 0.f;
        for (int f = 0; f < DHv; ++f) acc += Mh[hh*64 + f] * Wm[f*64 + e];
        Msg[i] = fmaxf(acc, 0.f);
    }
    __syncthreads();
    for (int i = tid; i < H*DHv; i += 256) {
        int hh = i >> 6, e = i & 63;
        float acc = Mh[i];
        for (int g = 0; g < H; ++g) acc += Adj[hh*H + g] * Msg[g*64 + e];
        concat[(size_t)bs*(H*DHv) + i] = acc;
    }
}

// ---------------- out projection: concat [4096,1216] @ w_o [1216,1024] ----------------
__global__ __launch_bounds__(256) void out_gemm(const float* __restrict__ A,
                                                const float* __restrict__ W,
                                                float* __restrict__ out) {
    const int mt = blockIdx.x, nt = blockIdx.y;
    const int KK = H*DHv;  // 1216

    __shared__ float As[16][68];
    __shared__ float Bs[16][68];

    const int tx = threadIdx.x, ty = threadIdx.y;
    const int tid = ty*16 + tx;
    const int m0 = mt*64, n0 = nt*64;

    const int arow = tid >> 2, acol4 = tid & 3;
    const int brow = tid >> 4, bcol4 = tid & 15;

    float acc[4][4] = {};

    for (int kt = 0; kt < KK; kt += 16) {
        float4 av = *(const float4*)&A[(size_t)(m0 + arow)*KK + kt + 4*acol4];
        float4 bv = *(const float4*)&W[(size_t)(kt + brow)*Dv + n0 + 4*bcol4];
        __syncthreads();
        As[4*acol4 + 0][arow] = av.x;
        As[4*acol4 + 1][arow] = av.y;
        As[4*acol4 + 2][arow] = av.z;
        As[4*acol4 + 3][arow] = av.w;
        *(float4*)&Bs[brow][4*bcol4] = bv;
        __syncthreads();
        #pragma unroll
        for (int kk = 0; kk < 16; ++kk) {
            float4 a = *(const float4*)&As[kk][ty*4];
            float4 b = *(const float4*)&Bs[kk][tx*4];
            acc[0][0] += a.x*b.x; acc[0][1] += a.x*b.y; acc[0][2] += a.x*b.z; acc[0][3] += a.x*b.w;
            acc[1][0] += a.y*b.x; acc[1][1] += a.y*b.y; acc[1][2] += a.y*b.z; acc[1][3] += a.y*b.w;
            acc[2][0] += a.z*b.x; acc[2][1] += a.z*b.y; acc[2][2] += a.z*b.z; acc[2][3] += a.z*b.w;
            acc[3][0] += a.w*b.x; acc[3][1] += a.w*b.y; acc[3][2] += a.w*b.z; acc[3][3] += a.w*b.w;
        }
    }

    #pragma unroll
    for (int i = 0; i < 4; ++i) {
        int grow = m0 + ty*4 + i;
        float4 o = make_float4(acc[i][0], acc[i][1], acc[i][2], acc[i][3]);
        *(float4*)&out[(size_t)grow*Dv + n0 + tx*4] = o;
    }
}

extern "C" void kernel_launch(void* const* d_in, const int* in_sizes, int n_in,
                              void* d_out, int out_size, void* d_ws, size_t ws_size,
                              hipStream_t stream) {
    const float* x      = (const float*)d_in[0];
    const float* coords = (const float*)d_in[1];
    const float* w_q    = (const float*)d_in[2];
    const float* w_k    = (const float*)d_in[3];
    const float* w_v    = (const float*)d_in[4];
    const float* wb1    = (const float*)d_in[5];
    const float* bb1    = (const float*)d_in[6];
    const float* wb2    = (const float*)d_in[7];
    const float* bb2    = (const float*)d_in[8];
    const float* w_mix  = (const float*)d_in[9];
    const float* adj    = (const float*)d_in[10];
    const float* w_o    = (const float*)d_in[11];

    float* ws   = (float*)d_ws;
    float* out  = (float*)d_out;
    float* bias = ws + BIAS_OFF;
    float* q    = ws + Q_OFF;
    float* kk   = q + QSZ;
    float* vv   = kk + QSZ;
    float* hd   = vv + QSZ;
    float* cc   = q;            // concat aliases q (dead after attention)

    bias_kernel<<<H, DHv, 0, stream>>>(coords, wb1, bb1, wb2, bb2, bias);
    qkv_gemm<<<dim3(64, H, 3), dim3(16, 16), 0, stream>>>(x, w_q, w_k, w_v, bias, q);
    attn_kernel<<<dim3(Sv/64, H, Bv), dim3(16, 16), 0, stream>>>(q, kk, vv, hd);
    mix_kernel<<<Bv*Sv, 256, 0, stream>>>(hd, w_mix, adj, cc);
    out_gemm<<<dim3(64, 16), dim3(16, 16), 0, stream>>>(cc, w_o, out);
}

// Round 2
// 864.142 us; speedup vs baseline: 1.9822x; 1.9822x over previous
//
#include <hip/hip_runtime.h>
#include <hip/hip_bf16.h>

#define H 19
#define Bv 2
#define Sv 2048
#define Dv 1024
#define DHv 64

typedef __bf16 bf16x8 __attribute__((ext_vector_type(8)));
typedef float f32x4 __attribute__((ext_vector_type(4)));

__device__ __forceinline__ ushort f2bf(float f) {
    uint u = __float_as_uint(f);
    u = (u + 0x7fffu + ((u >> 16) & 1u)) >> 16;
    return (ushort)u;
}

// ---------------- bias: relu(coords@wb1+bb1)@wb2+bb2 -> [H,DH] fp32 ----------------
__global__ void bias_kernel(const float* __restrict__ coords,
                            const float* __restrict__ wb1,
                            const float* __restrict__ bb1,
                            const float* __restrict__ wb2,
                            const float* __restrict__ bb2,
                            float* __restrict__ bias) {
    int h = blockIdx.x;
    int e = threadIdx.x;
    float c0 = coords[h*2 + 0];
    float c1 = coords[h*2 + 1];
    float acc = bb2[e];
    for (int d = 0; d < Dv; ++d) {
        float hd = c0*wb1[d] + c1*wb1[Dv + d] + bb1[d];
        hd = fmaxf(hd, 0.0f);
        acc += hd * wb2[d*DHv + e];
    }
    bias[h*DHv + e] = acc;
}

// ---------------- QKV projection (fp32 compute, bf16 outputs) ----------------
// t=0: q bf16 [B,H,S,DH], (acc+bias)*0.125
// t=1: k bf16 [B,H,S,DH]
// t=2: v bf16 TRANSPOSED [B,H,DH,S]
__global__ __launch_bounds__(256) void qkv_gemm(const float* __restrict__ x,
                                                const float* __restrict__ wq,
                                                const float* __restrict__ wk,
                                                const float* __restrict__ wv,
                                                const float* __restrict__ bias,
                                                ushort* __restrict__ qbf,
                                                ushort* __restrict__ kbf,
                                                ushort* __restrict__ vtbf) {
    const int mt = blockIdx.x;
    const int h  = blockIdx.y;
    const int t  = blockIdx.z;
    const float* w = (t == 0) ? wq : (t == 1) ? wk : wv;
    w += (size_t)h * Dv * DHv;

    __shared__ float As[16][68];
    __shared__ float Bs[16][68];
    __shared__ ushort VtL[64][65];

    const int tx = threadIdx.x, ty = threadIdx.y;
    const int tid = ty*16 + tx;
    const int m0 = mt*64;

    const int arow = tid >> 2, acol4 = tid & 3;
    const int brow = tid >> 4, bcol4 = tid & 15;

    float acc[4][4] = {};

    for (int kt = 0; kt < Dv; kt += 16) {
        float4 av = *(const float4*)&x[(size_t)(m0 + arow)*Dv + kt + 4*acol4];
        float4 bv = *(const float4*)&w[(size_t)(kt + brow)*DHv + 4*bcol4];
        __syncthreads();
        As[4*acol4 + 0][arow] = av.x;
        As[4*acol4 + 1][arow] = av.y;
        As[4*acol4 + 2][arow] = av.z;
        As[4*acol4 + 3][arow] = av.w;
        *(float4*)&Bs[brow][4*bcol4] = bv;
        __syncthreads();
        #pragma unroll
        for (int kk = 0; kk < 16; ++kk) {
            float4 a = *(const float4*)&As[kk][ty*4];
            float4 b = *(const float4*)&Bs[kk][tx*4];
            acc[0][0] += a.x*b.x; acc[0][1] += a.x*b.y; acc[0][2] += a.x*b.z; acc[0][3] += a.x*b.w;
            acc[1][0] += a.y*b.x; acc[1][1] += a.y*b.y; acc[1][2] += a.y*b.z; acc[1][3] += a.y*b.w;
            acc[2][0] += a.z*b.x; acc[2][1] += a.z*b.y; acc[2][2] += a.z*b.z; acc[2][3] += a.z*b.w;
            acc[3][0] += a.w*b.x; acc[3][1] += a.w*b.y; acc[3][2] += a.w*b.z; acc[3][3] += a.w*b.w;
        }
    }

    if (t != 2) {
        float4 bvq = make_float4(0.f, 0.f, 0.f, 0.f);
        if (t == 0) bvq = *(const float4*)&bias[h*DHv + tx*4];
        ushort* outp = (t == 0) ? qbf : kbf;
        #pragma unroll
        for (int i = 0; i < 4; ++i) {
            int grow = m0 + ty*4 + i;
            int bb = grow >> 11;
            int ss = grow & 2047;
            float a0 = acc[i][0], a1 = acc[i][1], a2 = acc[i][2], a3 = acc[i][3];
            if (t == 0) {
                a0 = (a0 + bvq.x)*0.125f; a1 = (a1 + bvq.y)*0.125f;
                a2 = (a2 + bvq.z)*0.125f; a3 = (a3 + bvq.w)*0.125f;
            }
            uint lo = (uint)f2bf(a0) | ((uint)f2bf(a1) << 16);
            uint hi = (uint)f2bf(a2) | ((uint)f2bf(a3) << 16);
            *(uint2*)&outp[(((size_t)bb*H + h)*Sv + ss)*DHv + tx*4] = make_uint2(lo, hi);
        }
    } else {
        // V: transpose 64x64 tile via LDS, store [B,H,DH,S]
        __syncthreads();
        #pragma unroll
        for (int i = 0; i < 4; ++i)
            #pragma unroll
            for (int j = 0; j < 4; ++j)
                VtL[ty*4 + i][tx*4 + j] = f2bf(acc[i][j]);
        __syncthreads();
        int dh = tid >> 2, sc4 = tid & 3;
        int bb = m0 >> 11;
        int s0 = (m0 & 2047) + sc4*16;
        uint u[8];
        #pragma unroll
        for (int kk2 = 0; kk2 < 8; ++kk2) {
            uint lo = VtL[sc4*16 + 2*kk2][dh];
            uint hi = VtL[sc4*16 + 2*kk2 + 1][dh];
            u[kk2] = lo | (hi << 16);
        }
        ushort* dst = vtbf + (((size_t)bb*H + h)*DHv + dh)*Sv + s0;
        *(uint4*)(dst)     = make_uint4(u[0], u[1], u[2], u[3]);
        *(uint4*)(dst + 8) = make_uint4(u[4], u[5], u[6], u[7]);
    }
}

// ---------------- MFMA flash attention ----------------
// Q pre-scaled bf16 [B,H,S,DH]; K bf16 [B,H,S,DH]; V bf16 [B,H,DH,S] (transposed)
// block: 4 waves, 64 q rows (16/wave); KV tiles of 64
__global__ __launch_bounds__(256) void attn_mfma(const ushort* __restrict__ qg,
                                                 const ushort* __restrict__ kg,
                                                 const ushort* __restrict__ vtg,
                                                 float* __restrict__ heads) {
    const int qt = blockIdx.x, h = blockIdx.y, b = blockIdx.z;
    const int tid = threadIdx.x;
    const int w = tid >> 6, lane = tid & 63;
    const int g = lane >> 4, r = lane & 15;

    __shared__ ushort Ks[4096];     // [kv 64][dh 64] swizzled
    __shared__ ushort Vs[4096];     // [dh 64][kv 64] swizzled
    __shared__ ushort Ps[4][1024];  // per-wave P [q 16][kv 64] swizzled

    const ushort* qb = qg + (((size_t)b*H + h)*Sv + qt*64 + w*16 + r)*DHv;
    const ushort* kb = kg + ((size_t)b*H + h)*Sv*DHv;
    const ushort* vb = vtg + ((size_t)b*H + h)*DHv*Sv;

    // Q A-fragments (held in registers for the whole block)
    bf16x8 qf0 = *(const bf16x8*)(qb + g*8);
    bf16x8 qf1 = *(const bf16x8*)(qb + 32 + g*8);

    float m_run[4], l_run[4];
    f32x4 o[4];
    const f32x4 zf = {0.f, 0.f, 0.f, 0.f};
    #pragma unroll
    for (int i = 0; i < 4; ++i) { m_run[i] = -1e30f; l_run[i] = 0.f; o[i] = zf; }

    for (int jt = 0; jt < Sv/64; ++jt) {
        __syncthreads();
        // stage K tile [64][64] and V tile [64 dh][64 kv], XOR-swizzled rows
        #pragma unroll
        for (int it = 0; it < 2; ++it) {
            int s2 = tid + it*256;
            int row = s2 >> 3, c = s2 & 7;
            bf16x8 kvv = *(const bf16x8*)(kb + (size_t)(jt*64 + row)*DHv + c*8);
            *(bf16x8*)((char*)Ks + row*128 + ((c*16) ^ ((row & 7) << 4))) = kvv;
            bf16x8 vvv = *(const bf16x8*)(vb + (size_t)row*Sv + jt*64 + c*8);
            *(bf16x8*)((char*)Vs + row*128 + ((c*16) ^ ((row & 7) << 4))) = vvv;
        }
        __syncthreads();

        // scores: D[q16][kv64] per wave, 8 MFMA
        f32x4 sc[4];
        sc[0] = zf; sc[1] = zf; sc[2] = zf; sc[3] = zf;
        #pragma unroll
        for (int kk = 0; kk < 2; ++kk) {
            bf16x8 qf = kk ? qf1 : qf0;
            #pragma unroll
            for (int nt = 0; nt < 4; ++nt) {
                int kvrow = r + 16*nt;
                bf16x8 bfg = *(const bf16x8*)((const char*)Ks + kvrow*128 +
                                              ((kk*64 + g*16) ^ ((kvrow & 7) << 4)));
                sc[nt] = __builtin_amdgcn_mfma_f32_16x16x32_bf16(qf, bfg, sc[nt], 0, 0, 0);
            }
        }

        // online softmax: rows = g*4+reg, 16 cols per lane spread over lane&15
        float corr[4];
        #pragma unroll
        for (int reg = 0; reg < 4; ++reg) {
            float mt = fmaxf(fmaxf(sc[0][reg], sc[1][reg]), fmaxf(sc[2][reg], sc[3][reg]));
            #pragma unroll
            for (int off = 1; off < 16; off <<= 1) mt = fmaxf(mt, __shfl_xor(mt, off));
            float mn = fmaxf(m_run[reg], mt);
            corr[reg] = __expf(m_run[reg] - mn);
            m_run[reg] = mn;
            float p0 = __expf(sc[0][reg] - mn);
            float p1 = __expf(sc[1][reg] - mn);
            float p2 = __expf(sc[2][reg] - mn);
            float p3 = __expf(sc[3][reg] - mn);
            sc[0][reg] = p0; sc[1][reg] = p1; sc[2][reg] = p2; sc[3][reg] = p3;
            float ls = p0 + p1 + p2 + p3;
            #pragma unroll
            for (int off = 1; off < 16; off <<= 1) ls += __shfl_xor(ls, off);
            l_run[reg] = l_run[reg]*corr[reg] + ls;
        }
        #pragma unroll
        for (int nt2 = 0; nt2 < 4; ++nt2)
            #pragma unroll
            for (int reg = 0; reg < 4; ++reg)
                o[nt2][reg] *= corr[reg];

        // write P (bf16) into per-wave LDS [q16][kv64], swizzled
        ushort* pw = Ps[w];
        #pragma unroll
        for (int nt = 0; nt < 4; ++nt) {
            #pragma unroll
            for (int reg = 0; reg < 4; ++reg) {
                int qq = g*4 + reg, kv = r + 16*nt;
                *(ushort*)((char*)pw + qq*128 + ((kv*2) ^ ((qq & 7) << 4))) = f2bf(sc[nt][reg]);
            }
        }

        // PV: O[q16][dh64] += P[q16][kv64] * V[kv64][dh64]
        #pragma unroll
        for (int kk = 0; kk < 2; ++kk) {
            bf16x8 pa = *(const bf16x8*)((const char*)pw + r*128 +
                                         ((kk*64 + g*16) ^ ((r & 7) << 4)));
            #pragma unroll
            for (int nt2 = 0; nt2 < 4; ++nt2) {
                int dh = r + 16*nt2;
                bf16x8 vf = *(const bf16x8*)((const char*)Vs + dh*128 +
                                             ((kk*64 + g*16) ^ ((dh & 7) << 4)));
                o[nt2] = __builtin_amdgcn_mfma_f32_16x16x32_bf16(pa, vf, o[nt2], 0, 0, 0);
            }
        }
    }

    // epilogue: normalize and store heads fp32 [B,H,S,DH]
    #pragma unroll
    for (int reg = 0; reg < 4; ++reg) {
        float inv = 1.0f / l_run[reg];
        int row = qt*64 + w*16 + g*4 + reg;
        float* hp = heads + (((size_t)b*H + h)*Sv + row)*DHv;
        #pragma unroll
        for (int nt2 = 0; nt2 < 4; ++nt2)
            hp[r + 16*nt2] = o[nt2][reg] * inv;
    }
}

// ---------------- GNN mix + concat: per (b,s) ----------------
__global__ __launch_bounds__(256) void mix_kernel(const float* __restrict__ heads,
                                                  const float* __restrict__ w_mix,
                                                  const float* __restrict__ adj,
                                                  float* __restrict__ concat) {
    const int bs = blockIdx.x;
    const int b = bs >> 11, s = bs & 2047;
    __shared__ float Mh[H*DHv];
    __shared__ float Msg[H*DHv];
    __shared__ float Wm[DHv*DHv];
    __shared__ float Adj[H*H];
    const int tid = threadIdx.x;

    for (int i = tid; i < DHv*DHv; i += 256) Wm[i] = w_mix[i];
    for (int i = tid; i < H*H; i += 256) Adj[i] = adj[i];
    for (int i = tid; i < H*DHv; i += 256) {
        int hh = i >> 6, e = i & 63;
        Mh[i] = heads[(((size_t)b*H + hh)*Sv + s)*DHv + e];
    }
    __syncthreads();
    for (int i = tid; i < H*DHv; i += 256) {
        int hh = i >> 6, e = i & 63;
        float acc = 0.f;
        for (int f = 0; f < DHv; ++f) acc += Mh[hh*64 + f] * Wm[f*64 + e];
        Msg[i] = fmaxf(acc, 0.f);
    }
    __syncthreads();
    for (int i = tid; i < H*DHv; i += 256) {
        int hh = i >> 6, e = i & 63;
        float acc = Mh[i];
        for (int gidx = 0; gidx < H; ++gidx) acc += Adj[hh*H + gidx] * Msg[gidx*64 + e];
        concat[(size_t)bs*(H*DHv) + i] = acc;
    }
}

// ---------------- out projection: concat [4096,1216] @ w_o [1216,1024] ----------------
__global__ __launch_bounds__(256) void out_gemm(const float* __restrict__ A,
                                                const float* __restrict__ W,
                                                float* __restrict__ out) {
    const int mt = blockIdx.x, nt = blockIdx.y;
    const int KK = H*DHv;  // 1216

    __shared__ float As[16][68];
    __shared__ float Bs[16][68];

    const int tx = threadIdx.x, ty = threadIdx.y;
    const int tid = ty*16 + tx;
    const int m0 = mt*64, n0 = nt*64;

    const int arow = tid >> 2, acol4 = tid & 3;
    const int brow = tid >> 4, bcol4 = tid & 15;

    float acc[4][4] = {};

    for (int kt = 0; kt < KK; kt += 16) {
        float4 av = *(const float4*)&A[(size_t)(m0 + arow)*KK + kt + 4*acol4];
        float4 bv = *(const float4*)&W[(size_t)(kt + brow)*Dv + n0 + 4*bcol4];
        __syncthreads();
        As[4*acol4 + 0][arow] = av.x;
        As[4*acol4 + 1][arow] = av.y;
        As[4*acol4 + 2][arow] = av.z;
        As[4*acol4 + 3][arow] = av.w;
        *(float4*)&Bs[brow][4*bcol4] = bv;
        __syncthreads();
        #pragma unroll
        for (int kk = 0; kk < 16; ++kk) {
            float4 a = *(const float4*)&As[kk][ty*4];
            float4 b = *(const float4*)&Bs[kk][tx*4];
            acc[0][0] += a.x*b.x; acc[0][1] += a.x*b.y; acc[0][2] += a.x*b.z; acc[0][3] += a.x*b.w;
            acc[1][0] += a.y*b.x; acc[1][1] += a.y*b.y; acc[1][2] += a.y*b.z; acc[1][3] += a.y*b.w;
            acc[2][0] += a.z*b.x; acc[2][1] += a.z*b.y; acc[2][2] += a.z*b.z; acc[2][3] += a.z*b.w;
            acc[3][0] += a.w*b.x; acc[3][1] += a.w*b.y; acc[3][2] += a.w*b.z; acc[3][3] += a.w*b.w;
        }
    }

    #pragma unroll
    for (int i = 0; i < 4; ++i) {
        int grow = m0 + ty*4 + i;
        float4 ovv = make_float4(acc[i][0], acc[i][1], acc[i][2], acc[i][3]);
        *(float4*)&out[(size_t)grow*Dv + n0 + tx*4] = ovv;
    }
}

extern "C" void kernel_launch(void* const* d_in, const int* in_sizes, int n_in,
                              void* d_out, int out_size, void* d_ws, size_t ws_size,
                              hipStream_t stream) {
    const float* x      = (const float*)d_in[0];
    const float* coords = (const float*)d_in[1];
    const float* w_q    = (const float*)d_in[2];
    const float* w_k    = (const float*)d_in[3];
    const float* w_v    = (const float*)d_in[4];
    const float* wb1    = (const float*)d_in[5];
    const float* bb1    = (const float*)d_in[6];
    const float* wb2    = (const float*)d_in[7];
    const float* bb2    = (const float*)d_in[8];
    const float* w_mix  = (const float*)d_in[9];
    const float* adj    = (const float*)d_in[10];
    const float* w_o    = (const float*)d_in[11];

    char* ws = (char*)d_ws;
    const size_t QKV_BYTES = (size_t)Bv*H*Sv*DHv*2;      // 9,961,472
    const size_t HEADS_BYTES = (size_t)Bv*H*Sv*DHv*4;    // 19,922,944

    float*  bias = (float*)(ws + 0);
    ushort* qbf  = (ushort*)(ws + 16384);
    ushort* kbf  = (ushort*)(ws + 16384 + QKV_BYTES);
    ushort* vtbf = (ushort*)(ws + 16384 + 2*QKV_BYTES);
    float*  hd   = (float*)(ws + 16384 + 3*QKV_BYTES);
    float*  cc   = (float*)(ws + 16384 + 3*QKV_BYTES + HEADS_BYTES);
    float*  out  = (float*)d_out;

    bias_kernel<<<H, DHv, 0, stream>>>(coords, wb1, bb1, wb2, bb2, bias);
    qkv_gemm<<<dim3(64, H, 3), dim3(16, 16), 0, stream>>>(x, w_q, w_k, w_v, bias, qbf, kbf, vtbf);
    attn_mfma<<<dim3(Sv/64, H, Bv), 256, 0, stream>>>(qbf, kbf, vtbf, hd);
    mix_kernel<<<Bv*Sv, 256, 0, stream>>>(hd, w_mix, adj, cc);
    out_gemm<<<dim3(64, 16), dim3(16, 16), 0, stream>>>(cc, w_o, out);
}

// Round 3
// 402.370 us; speedup vs baseline: 4.2570x; 2.1476x over previous
//
#include <hip/hip_runtime.h>
#include <hip/hip_bf16.h>

#define H 19
#define Bv 2
#define Sv 2048
#define Dv 1024
#define DHv 64

typedef __bf16 bf16x8 __attribute__((ext_vector_type(8)));
typedef float f32x4 __attribute__((ext_vector_type(4)));

__device__ __forceinline__ ushort f2bf(float f) {
    uint u = __float_as_uint(f);
    u = (u + 0x7fffu + ((u >> 16) & 1u)) >> 16;
    return (ushort)u;
}

// ---------------- prep: x -> bf16 ----------------
__global__ __launch_bounds__(256) void prep_x(const float* __restrict__ x,
                                              ushort* __restrict__ xbf) {
    int idx = (blockIdx.x*256 + threadIdx.x)*8;
    float4 a = *(const float4*)&x[idx];
    float4 b = *(const float4*)&x[idx+4];
    uint4 o;
    o.x = (uint)f2bf(a.x) | ((uint)f2bf(a.y) << 16);
    o.y = (uint)f2bf(a.z) | ((uint)f2bf(a.w) << 16);
    o.z = (uint)f2bf(b.x) | ((uint)f2bf(b.y) << 16);
    o.w = (uint)f2bf(b.z) | ((uint)f2bf(b.w) << 16);
    *(uint4*)&xbf[idx] = o;
}

// ---------------- prep: pack+transpose qkv weights -> wpackT [H][192][1024] bf16 ----------------
// block (dt, t, h): transpose 64x64 tile of w_t[h] [1024][64]
__global__ __launch_bounds__(256) void prep_w(const float* __restrict__ wq,
                                              const float* __restrict__ wk,
                                              const float* __restrict__ wv,
                                              ushort* __restrict__ wpackT) {
    const int dt = blockIdx.x, t = blockIdx.y, h = blockIdx.z;
    const float* w = (t == 0) ? wq : (t == 1) ? wk : wv;
    w += (size_t)h*Dv*DHv;
    __shared__ ushort T[64*65];
    const int tid = threadIdx.x;
    int row = tid >> 2, c4 = tid & 3;           // row = d-local, 16 floats each
    #pragma unroll
    for (int q4 = 0; q4 < 4; ++q4) {
        float4 v = *(const float4*)&w[(size_t)(dt*64+row)*DHv + c4*16 + q4*4];
        T[(c4*16 + q4*4 + 0)*65 + row] = f2bf(v.x);
        T[(c4*16 + q4*4 + 1)*65 + row] = f2bf(v.y);
        T[(c4*16 + q4*4 + 2)*65 + row] = f2bf(v.z);
        T[(c4*16 + q4*4 + 3)*65 + row] = f2bf(v.w);
    }
    __syncthreads();
    #pragma unroll
    for (int i = 0; i < 2; ++i) {
        int f = tid + i*256;
        int e = f >> 3, c = f & 7;
        uint u[4];
        #pragma unroll
        for (int j = 0; j < 4; ++j) {
            uint lo = T[e*65 + c*8 + 2*j];
            uint hi = T[e*65 + c*8 + 2*j + 1];
            u[j] = lo | (hi << 16);
        }
        *(uint4*)&wpackT[((size_t)h*192 + t*64 + e)*Dv + dt*64 + c*8] = make_uint4(u[0],u[1],u[2],u[3]);
    }
}

// ---------------- prep: transpose w_o [1216][1024] -> w_oT [1024][1216] bf16 ----------------
__global__ __launch_bounds__(256) void prep_wo(const float* __restrict__ wo,
                                               ushort* __restrict__ woT) {
    const int nt = blockIdx.x, kt2 = blockIdx.y;   // nt: 16 col tiles, kt2: 19 row tiles
    __shared__ ushort T[64*65];
    const int tid = threadIdx.x;
    int row = tid >> 2, c4 = tid & 3;
    #pragma unroll
    for (int q4 = 0; q4 < 4; ++q4) {
        float4 v = *(const float4*)&wo[(size_t)(kt2*64+row)*Dv + nt*64 + c4*16 + q4*4];
        T[(c4*16 + q4*4 + 0)*65 + row] = f2bf(v.x);
        T[(c4*16 + q4*4 + 1)*65 + row] = f2bf(v.y);
        T[(c4*16 + q4*4 + 2)*65 + row] = f2bf(v.z);
        T[(c4*16 + q4*4 + 3)*65 + row] = f2bf(v.w);
    }
    __syncthreads();
    #pragma unroll
    for (int i = 0; i < 2; ++i) {
        int f = tid + i*256;
        int e = f >> 3, c = f & 7;
        uint u[4];
        #pragma unroll
        for (int j = 0; j < 4; ++j) {
            uint lo = T[e*65 + c*8 + 2*j];
            uint hi = T[e*65 + c*8 + 2*j + 1];
            u[j] = lo | (hi << 16);
        }
        *(uint4*)&woT[(size_t)(nt*64+e)*(H*DHv) + kt2*64 + c*8] = make_uint4(u[0],u[1],u[2],u[3]);
    }
}

// ---------------- bias: relu(coords@wb1+bb1)@wb2+bb2 -> [H,DH] fp32 ----------------
__global__ void bias_kernel(const float* __restrict__ coords,
                            const float* __restrict__ wb1,
                            const float* __restrict__ bb1,
                            const float* __restrict__ wb2,
                            const float* __restrict__ bb2,
                            float* __restrict__ bias) {
    int h = blockIdx.x;
    int e = threadIdx.x;
    float c0 = coords[h*2 + 0];
    float c1 = coords[h*2 + 1];
    float acc = bb2[e];
    for (int d = 0; d < Dv; ++d) {
        float hd = c0*wb1[d] + c1*wb1[Dv + d] + bb1[d];
        hd = fmaxf(hd, 0.0f);
        acc += hd * wb2[d*DHv + e];
    }
    bias[h*DHv + e] = acc;
}

// ---------------- QKV projection, bf16 MFMA ----------------
// block (mt, h): 64 rows x 192 cols (q|k|v), 4 waves x 48 cols, K=1024 in steps of 64
__global__ __launch_bounds__(256) void qkv_mfma(const ushort* __restrict__ xbf,
                                                const ushort* __restrict__ wpackT,
                                                const float* __restrict__ bias,
                                                ushort* __restrict__ qbf,
                                                ushort* __restrict__ kbf,
                                                ushort* __restrict__ vtbf) {
    const int mt = blockIdx.x, h = blockIdx.y;
    const int m0 = mt*64;
    const int tid = threadIdx.x;
    const int w = tid >> 6, lane = tid & 63;
    const int g = lane >> 4, r = lane & 15;

    __shared__ char lds[8192 + 24576];
    char* Xs = lds;                 // [64 rows][64 k] bf16 swizzled (128 B rows)
    char* Ws = lds + 8192;          // [192 n-rows][64 k] bf16 swizzled
    ushort* VtL = (ushort*)lds;     // reused for v transpose (64*66*2 = 8448 B)

    f32x4 acc[4][3];
    const f32x4 zf = {0.f,0.f,0.f,0.f};
    #pragma unroll
    for (int m = 0; m < 4; ++m)
        #pragma unroll
        for (int n = 0; n < 3; ++n) acc[m][n] = zf;

    const ushort* xb = xbf + (size_t)m0*Dv;
    const ushort* wb = wpackT + (size_t)h*192*Dv;

    for (int kt = 0; kt < Dv; kt += 64) {
        __syncthreads();
        #pragma unroll
        for (int i = 0; i < 2; ++i) {
            int f = tid + i*256;
            int row = f >> 3, c = f & 7;
            *(bf16x8*)(Xs + row*128 + ((c*16) ^ ((row & 7) << 4))) =
                *(const bf16x8*)(xb + (size_t)row*Dv + kt + c*8);
        }
        #pragma unroll
        for (int i = 0; i < 6; ++i) {
            int f = tid + i*256;
            int row = f >> 3, c = f & 7;
            *(bf16x8*)(Ws + row*128 + ((c*16) ^ ((row & 7) << 4))) =
                *(const bf16x8*)(wb + (size_t)row*Dv + kt + c*8);
        }
        __syncthreads();
        #pragma unroll
        for (int kk = 0; kk < 2; ++kk) {
            bf16x8 a[4], bfr[3];
            #pragma unroll
            for (int m = 0; m < 4; ++m) {
                int row = m*16 + r;
                a[m] = *(const bf16x8*)(Xs + row*128 + (((kk*32 + g*8)*2) ^ ((row & 7) << 4)));
            }
            #pragma unroll
            for (int n = 0; n < 3; ++n) {
                int row = (w*3 + n)*16 + r;
                bfr[n] = *(const bf16x8*)(Ws + row*128 + (((kk*32 + g*8)*2) ^ ((row & 7) << 4)));
            }
            #pragma unroll
            for (int m = 0; m < 4; ++m)
                #pragma unroll
                for (int n = 0; n < 3; ++n)
                    acc[m][n] = __builtin_amdgcn_mfma_f32_16x16x32_bf16(a[m], bfr[n], acc[m][n], 0, 0, 0);
        }
    }

    __syncthreads();   // all MFMA LDS reads done; safe to reuse lds as VtL

    const int bb = m0 >> 11;
    const int s0 = m0 & 2047;
    #pragma unroll
    for (int m = 0; m < 4; ++m) {
        #pragma unroll
        for (int n = 0; n < 3; ++n) {
            int ng = w*3 + n;
            int t = ng >> 2;
            int e = (ng & 3)*16 + r;
            if (t == 0) {
                float bv = bias[h*DHv + e];
                #pragma unroll
                for (int reg = 0; reg < 4; ++reg) {
                    int ss = s0 + m*16 + g*4 + reg;
                    qbf[(((size_t)bb*H + h)*Sv + ss)*DHv + e] = f2bf((acc[m][n][reg] + bv)*0.125f);
                }
            } else if (t == 1) {
                #pragma unroll
                for (int reg = 0; reg < 4; ++reg) {
                    int ss = s0 + m*16 + g*4 + reg;
                    kbf[(((size_t)bb*H + h)*Sv + ss)*DHv + e] = f2bf(acc[m][n][reg]);
                }
            } else {
                #pragma unroll
                for (int reg = 0; reg < 4; ++reg) {
                    int sl = m*16 + g*4 + reg;
                    VtL[e*66 + sl] = f2bf(acc[m][n][reg]);
                }
            }
        }
    }
    __syncthreads();
    // write v transposed: vtbf [B,H,DH,S]
    #pragma unroll
    for (int i = 0; i < 2; ++i) {
        int f = tid + i*256;
        int dh = f >> 3, sc = f & 7;
        uint u[4];
        #pragma unroll
        for (int j = 0; j < 4; ++j) {
            uint lo = VtL[dh*66 + sc*8 + 2*j];
            uint hi = VtL[dh*66 + sc*8 + 2*j + 1];
            u[j] = lo | (hi << 16);
        }
        *(uint4*)&vtbf[(((size_t)bb*H + h)*DHv + dh)*Sv + s0 + sc*8] = make_uint4(u[0],u[1],u[2],u[3]);
    }
}

// ---------------- MFMA flash attention (unchanged from round 2) ----------------
__global__ __launch_bounds__(256) void attn_mfma(const ushort* __restrict__ qg,
                                                 const ushort* __restrict__ kg,
                                                 const ushort* __restrict__ vtg,
                                                 float* __restrict__ heads) {
    const int qt = blockIdx.x, h = blockIdx.y, b = blockIdx.z;
    const int tid = threadIdx.x;
    const int w = tid >> 6, lane = tid & 63;
    const int g = lane >> 4, r = lane & 15;

    __shared__ ushort Ks[4096];
    __shared__ ushort Vs[4096];
    __shared__ ushort Ps[4][1024];

    const ushort* qb = qg + (((size_t)b*H + h)*Sv + qt*64 + w*16 + r)*DHv;
    const ushort* kb = kg + ((size_t)b*H + h)*Sv*DHv;
    const ushort* vb = vtg + ((size_t)b*H + h)*DHv*Sv;

    bf16x8 qf0 = *(const bf16x8*)(qb + g*8);
    bf16x8 qf1 = *(const bf16x8*)(qb + 32 + g*8);

    float m_run[4], l_run[4];
    f32x4 o[4];
    const f32x4 zf = {0.f, 0.f, 0.f, 0.f};
    #pragma unroll
    for (int i = 0; i < 4; ++i) { m_run[i] = -1e30f; l_run[i] = 0.f; o[i] = zf; }

    for (int jt = 0; jt < Sv/64; ++jt) {
        __syncthreads();
        #pragma unroll
        for (int it = 0; it < 2; ++it) {
            int s2 = tid + it*256;
            int row = s2 >> 3, c = s2 & 7;
            bf16x8 kvv = *(const bf16x8*)(kb + (size_t)(jt*64 + row)*DHv + c*8);
            *(bf16x8*)((char*)Ks + row*128 + ((c*16) ^ ((row & 7) << 4))) = kvv;
            bf16x8 vvv = *(const bf16x8*)(vb + (size_t)row*Sv + jt*64 + c*8);
            *(bf16x8*)((char*)Vs + row*128 + ((c*16) ^ ((row & 7) << 4))) = vvv;
        }
        __syncthreads();

        f32x4 sc[4];
        sc[0] = zf; sc[1] = zf; sc[2] = zf; sc[3] = zf;
        #pragma unroll
        for (int kk = 0; kk < 2; ++kk) {
            bf16x8 qf = kk ? qf1 : qf0;
            #pragma unroll
            for (int nt = 0; nt < 4; ++nt) {
                int kvrow = r + 16*nt;
                bf16x8 bfg = *(const bf16x8*)((const char*)Ks + kvrow*128 +
                                              ((kk*64 + g*16) ^ ((kvrow & 7) << 4)));
                sc[nt] = __builtin_amdgcn_mfma_f32_16x16x32_bf16(qf, bfg, sc[nt], 0, 0, 0);
            }
        }

        float corr[4];
        #pragma unroll
        for (int reg = 0; reg < 4; ++reg) {
            float mt = fmaxf(fmaxf(sc[0][reg], sc[1][reg]), fmaxf(sc[2][reg], sc[3][reg]));
            #pragma unroll
            for (int off = 1; off < 16; off <<= 1) mt = fmaxf(mt, __shfl_xor(mt, off));
            float mn = fmaxf(m_run[reg], mt);
            corr[reg] = __expf(m_run[reg] - mn);
            m_run[reg] = mn;
            float p0 = __expf(sc[0][reg] - mn);
            float p1 = __expf(sc[1][reg] - mn);
            float p2 = __expf(sc[2][reg] - mn);
            float p3 = __expf(sc[3][reg] - mn);
            sc[0][reg] = p0; sc[1][reg] = p1; sc[2][reg] = p2; sc[3][reg] = p3;
            float ls = p0 + p1 + p2 + p3;
            #pragma unroll
            for (int off = 1; off < 16; off <<= 1) ls += __shfl_xor(ls, off);
            l_run[reg] = l_run[reg]*corr[reg] + ls;
        }
        #pragma unroll
        for (int nt2 = 0; nt2 < 4; ++nt2)
            #pragma unroll
            for (int reg = 0; reg < 4; ++reg)
                o[nt2][reg] *= corr[reg];

        ushort* pw = Ps[w];
        #pragma unroll
        for (int nt = 0; nt < 4; ++nt) {
            #pragma unroll
            for (int reg = 0; reg < 4; ++reg) {
                int qq = g*4 + reg, kv = r + 16*nt;
                *(ushort*)((char*)pw + qq*128 + ((kv*2) ^ ((qq & 7) << 4))) = f2bf(sc[nt][reg]);
            }
        }

        #pragma unroll
        for (int kk = 0; kk < 2; ++kk) {
            bf16x8 pa = *(const bf16x8*)((const char*)pw + r*128 +
                                         ((kk*64 + g*16) ^ ((r & 7) << 4)));
            #pragma unroll
            for (int nt2 = 0; nt2 < 4; ++nt2) {
                int dh = r + 16*nt2;
                bf16x8 vf = *(const bf16x8*)((const char*)Vs + dh*128 +
                                             ((kk*64 + g*16) ^ ((dh & 7) << 4)));
                o[nt2] = __builtin_amdgcn_mfma_f32_16x16x32_bf16(pa, vf, o[nt2], 0, 0, 0);
            }
        }
    }

    #pragma unroll
    for (int reg = 0; reg < 4; ++reg) {
        float inv = 1.0f / l_run[reg];
        int row = qt*64 + w*16 + g*4 + reg;
        float* hp = heads + (((size_t)b*H + h)*Sv + row)*DHv;
        #pragma unroll
        for (int nt2 = 0; nt2 < 4; ++nt2)
            hp[r + 16*nt2] = o[nt2][reg] * inv;
    }
}

// ---------------- GNN mix + concat (bf16 out): per (b,s) ----------------
__global__ __launch_bounds__(256) void mix_kernel(const float* __restrict__ heads,
                                                  const float* __restrict__ w_mix,
                                                  const float* __restrict__ adj,
                                                  ushort* __restrict__ concat) {
    const int bs = blockIdx.x;
    const int b = bs >> 11, s = bs & 2047;
    __shared__ float Mh[H*DHv];
    __shared__ float Msg[H*DHv];
    __shared__ float Wm[DHv*DHv];
    __shared__ float Adj[H*H];
    const int tid = threadIdx.x;

    for (int i = tid; i < DHv*DHv; i += 256) Wm[i] = w_mix[i];
    for (int i = tid; i < H*H; i += 256) Adj[i] = adj[i];
    for (int i = tid; i < H*DHv; i += 256) {
        int hh = i >> 6, e = i & 63;
        Mh[i] = heads[(((size_t)b*H + hh)*Sv + s)*DHv + e];
    }
    __syncthreads();
    for (int i = tid; i < H*DHv; i += 256) {
        int hh = i >> 6, e = i & 63;
        float acc = 0.f;
        for (int f = 0; f < DHv; ++f) acc += Mh[hh*64 + f] * Wm[f*64 + e];
        Msg[i] = fmaxf(acc, 0.f);
    }
    __syncthreads();
    for (int i = tid; i < H*DHv; i += 256) {
        int hh = i >> 6, e = i & 63;
        float acc = Mh[i];
        for (int gidx = 0; gidx < H; ++gidx) acc += Adj[hh*H + gidx] * Msg[gidx*64 + e];
        concat[(size_t)bs*(H*DHv) + i] = f2bf(acc);
    }
}

// ---------------- out projection, bf16 MFMA: [4096,1216] @ [1216,1024] ----------------
// block (mt, nt2): 64 rows x 128 cols; 4 waves: wave w = rows w*16..+15, 8 n-tiles
__global__ __launch_bounds__(256) void out_mfma(const ushort* __restrict__ cc,
                                                const ushort* __restrict__ woT,
                                                float* __restrict__ out) {
    const int mt = blockIdx.x, nt2 = blockIdx.y;
    const int m0 = mt*64, n0 = nt2*128;
    const int KK = H*DHv;  // 1216
    const int tid = threadIdx.x;
    const int w = tid >> 6, lane = tid & 63;
    const int g = lane >> 4, r = lane & 15;

    __shared__ char lds[8192 + 16384];
    char* As = lds;            // [64 m][64 k] bf16 swizzled
    char* Bs = lds + 8192;     // [128 n][64 k] bf16 swizzled

    f32x4 acc[8];
    const f32x4 zf = {0.f,0.f,0.f,0.f};
    #pragma unroll
    for (int n = 0; n < 8; ++n) acc[n] = zf;

    for (int kt = 0; kt < KK; kt += 64) {
        __syncthreads();
        #pragma unroll
        for (int i = 0; i < 2; ++i) {
            int f = tid + i*256;
            int row = f >> 3, c = f & 7;
            *(bf16x8*)(As + row*128 + ((c*16) ^ ((row & 7) << 4))) =
                *(const bf16x8*)(cc + (size_t)(m0 + row)*KK + kt + c*8);
        }
        #pragma unroll
        for (int i = 0; i < 4; ++i) {
            int f = tid + i*256;
            int row = f >> 3, c = f & 7;
            *(bf16x8*)(Bs + row*128 + ((c*16) ^ ((row & 7) << 4))) =
                *(const bf16x8*)(woT + (size_t)(n0 + row)*KK + kt + c*8);
        }
        __syncthreads();
        #pragma unroll
        for (int kk = 0; kk < 2; ++kk) {
            int arow = w*16 + r;
            bf16x8 a = *(const bf16x8*)(As + arow*128 + (((kk*32 + g*8)*2) ^ ((arow & 7) << 4)));
            #pragma unroll
            for (int n = 0; n < 8; ++n) {
                int brow = n*16 + r;
                bf16x8 bfr = *(const bf16x8*)(Bs + brow*128 + (((kk*32 + g*8)*2) ^ ((brow & 7) << 4)));
                acc[n] = __builtin_amdgcn_mfma_f32_16x16x32_bf16(a, bfr, acc[n], 0, 0, 0);
            }
        }
    }

    #pragma unroll
    for (int n = 0; n < 8; ++n) {
        #pragma unroll
        for (int reg = 0; reg < 4; ++reg) {
            int grow = m0 + w*16 + g*4 + reg;
            out[(size_t)grow*Dv + n0 + n*16 + r] = acc[n][reg];
        }
    }
}

extern "C" void kernel_launch(void* const* d_in, const int* in_sizes, int n_in,
                              void* d_out, int out_size, void* d_ws, size_t ws_size,
                              hipStream_t stream) {
    const float* x      = (const float*)d_in[0];
    const float* coords = (const float*)d_in[1];
    const float* w_q    = (const float*)d_in[2];
    const float* w_k    = (const float*)d_in[3];
    const float* w_v    = (const float*)d_in[4];
    const float* wb1    = (const float*)d_in[5];
    const float* bb1    = (const float*)d_in[6];
    const float* wb2    = (const float*)d_in[7];
    const float* bb2    = (const float*)d_in[8];
    const float* w_mix  = (const float*)d_in[9];
    const float* adj    = (const float*)d_in[10];
    const float* w_o    = (const float*)d_in[11];

    char* ws = (char*)d_ws;
    const size_t QKV_BYTES   = (size_t)Bv*H*Sv*DHv*2;     // 9,961,472
    const size_t HEADS_BYTES = (size_t)Bv*H*Sv*DHv*4;     // 19,922,944
    const size_t XBF_BYTES   = (size_t)Bv*Sv*Dv*2;        // 8,388,608
    const size_t WPK_BYTES   = (size_t)H*192*Dv*2;        // 7,471,104

    size_t off = 0;
    float*  bias = (float*)(ws + off);  off += 16384;
    ushort* qbf  = (ushort*)(ws + off); off += QKV_BYTES;
    ushort* kbf  = (ushort*)(ws + off); off += QKV_BYTES;
    ushort* vtbf = (ushort*)(ws + off); off += QKV_BYTES;
    float*  hd   = (float*)(ws + off);  off += HEADS_BYTES;
    ushort* xbf  = (ushort*)(ws + off); off += XBF_BYTES;
    ushort* wpkT = (ushort*)(ws + off); off += WPK_BYTES;
    ushort* woT  = (ushort*)(ws + off); off += (size_t)Dv*(H*DHv)*2;
    ushort* cc   = xbf;   // concat aliases xbf+wpackT region (dead after qkv_mfma)
    float*  out  = (float*)d_out;

    prep_x<<<(Bv*Sv*Dv)/(256*8), 256, 0, stream>>>(x, xbf);
    prep_w<<<dim3(16, 3, H), 256, 0, stream>>>(w_q, w_k, w_v, wpkT);
    prep_wo<<<dim3(16, H), 256, 0, stream>>>(w_o, woT);
    bias_kernel<<<H, DHv, 0, stream>>>(coords, wb1, bb1, wb2, bb2, bias);
    qkv_mfma<<<dim3(64, H), 256, 0, stream>>>(xbf, wpkT, bias, qbf, kbf, vtbf);
    attn_mfma<<<dim3(Sv/64, H, Bv), 256, 0, stream>>>(qbf, kbf, vtbf, hd);
    mix_kernel<<<Bv*Sv, 256, 0, stream>>>(hd, w_mix, adj, cc);
    out_mfma<<<dim3(64, 8), 256, 0, stream>>>(cc, woT, out);
}

// Round 4
// 346.823 us; speedup vs baseline: 4.9388x; 1.1602x over previous
//
#include <hip/hip_runtime.h>
#include <hip/hip_bf16.h>

#define H 19
#define Bv 2
#define Sv 2048
#define Dv 1024
#define DHv 64
#define KK2 (2*H*DHv)   // 2432
#define QSCALE 0.125f

typedef __bf16 bf16x8 __attribute__((ext_vector_type(8)));
typedef float f32x4 __attribute__((ext_vector_type(4)));

__device__ __forceinline__ ushort f2bf(float f) {
    uint u = __float_as_uint(f);
    u = (u + 0x7fffu + ((u >> 16) & 1u)) >> 16;
    return (ushort)u;
}

__device__ __forceinline__ uint cvtpk(float lo, float hi) {
    uint r;
    asm("v_cvt_pk_bf16_f32 %0, %1, %2" : "=v"(r) : "v"(lo), "v"(hi));
    return r;
}

// async global->LDS, 16B per lane; dest = wave-uniform base + lane*16
__device__ __forceinline__ void gll16(const ushort* g, ushort* l) {
    __builtin_amdgcn_global_load_lds(
        (const __attribute__((address_space(1))) unsigned int*)g,
        (__attribute__((address_space(3))) unsigned int*)l, 16, 0, 0);
}

// ---------------- prep: x -> bf16 ----------------
__global__ __launch_bounds__(256) void prep_x(const float* __restrict__ x,
                                              ushort* __restrict__ xbf) {
    int idx = (blockIdx.x*256 + threadIdx.x)*8;
    float4 a = *(const float4*)&x[idx];
    float4 b = *(const float4*)&x[idx+4];
    uint4 o;
    o.x = cvtpk(a.x, a.y);
    o.y = cvtpk(a.z, a.w);
    o.z = cvtpk(b.x, b.y);
    o.w = cvtpk(b.z, b.w);
    *(uint4*)&xbf[idx] = o;
}

// ---------------- prep: pack+transpose qkv weights -> wpackT [H][192][1024] bf16 ----------------
__global__ __launch_bounds__(256) void prep_w(const float* __restrict__ wq,
                                              const float* __restrict__ wk,
                                              const float* __restrict__ wv,
                                              ushort* __restrict__ wpackT) {
    const int dt = blockIdx.x, t = blockIdx.y, h = blockIdx.z;
    const float* w = (t == 0) ? wq : (t == 1) ? wk : wv;
    w += (size_t)h*Dv*DHv;
    __shared__ ushort T[64*65];
    const int tid = threadIdx.x;
    int row = tid >> 2, c4 = tid & 3;
    #pragma unroll
    for (int q4 = 0; q4 < 4; ++q4) {
        float4 v = *(const float4*)&w[(size_t)(dt*64+row)*DHv + c4*16 + q4*4];
        T[(c4*16 + q4*4 + 0)*65 + row] = f2bf(v.x);
        T[(c4*16 + q4*4 + 1)*65 + row] = f2bf(v.y);
        T[(c4*16 + q4*4 + 2)*65 + row] = f2bf(v.z);
        T[(c4*16 + q4*4 + 3)*65 + row] = f2bf(v.w);
    }
    __syncthreads();
    #pragma unroll
    for (int i = 0; i < 2; ++i) {
        int f = tid + i*256;
        int e = f >> 3, c = f & 7;
        uint u[4];
        #pragma unroll
        for (int j = 0; j < 4; ++j) {
            uint lo = T[e*65 + c*8 + 2*j];
            uint hi = T[e*65 + c*8 + 2*j + 1];
            u[j] = lo | (hi << 16);
        }
        *(uint4*)&wpackT[((size_t)h*192 + t*64 + e)*Dv + dt*64 + c*8] = make_uint4(u[0],u[1],u[2],u[3]);
    }
}

// ---------------- prep: w_mix -> transposed bf16 [e][f] ----------------
__global__ __launch_bounds__(256) void prep_wmix(const float* __restrict__ wm,
                                                 ushort* __restrict__ wmixT) {
    int tid = threadIdx.x;
    int e = tid >> 2, f4 = tid & 3;
    #pragma unroll
    for (int j = 0; j < 16; ++j) {
        int f = f4*16 + j;
        wmixT[e*64 + f] = f2bf(wm[f*64 + e]);
    }
}

// ---------------- prep: woTcat [1024 n][2432 k] = [w_o^T | (adj-folded w_o)^T] ----------------
__global__ __launch_bounds__(256) void prep_wo2(const float* __restrict__ wo,
                                                const float* __restrict__ adj,
                                                ushort* __restrict__ woTcat) {
    const int nt = blockIdx.x;   // 16 n-tiles
    const int g  = blockIdx.y;   // 19 e-tiles
    const int tid = threadIdx.x;
    const int e = tid >> 2, n4 = tid & 3;
    float acc[16];
    float part1[16];
    #pragma unroll
    for (int j = 0; j < 16; ++j) { acc[j] = 0.f; part1[j] = 0.f; }
    for (int h2 = 0; h2 < H; ++h2) {
        float a = adj[h2*H + g];
        const float* rp = wo + (size_t)(h2*64 + e)*Dv + nt*64 + n4*16;
        #pragma unroll
        for (int j4 = 0; j4 < 4; ++j4) {
            float4 v = *(const float4*)&rp[j4*4];
            acc[j4*4+0] += a*v.x; acc[j4*4+1] += a*v.y;
            acc[j4*4+2] += a*v.z; acc[j4*4+3] += a*v.w;
            if (h2 == g) {
                part1[j4*4+0] = v.x; part1[j4*4+1] = v.y;
                part1[j4*4+2] = v.z; part1[j4*4+3] = v.w;
            }
        }
    }
    #pragma unroll
    for (int j = 0; j < 16; ++j) {
        int n = nt*64 + n4*16 + j;
        woTcat[(size_t)n*KK2 + g*64 + e]            = f2bf(part1[j]);
        woTcat[(size_t)n*KK2 + H*DHv + g*64 + e]    = f2bf(acc[j]);
    }
}

// ---------------- bias: relu(coords@wb1+bb1)@wb2+bb2 -> [H,DH] fp32 ----------------
__global__ void bias_kernel(const float* __restrict__ coords,
                            const float* __restrict__ wb1,
                            const float* __restrict__ bb1,
                            const float* __restrict__ wb2,
                            const float* __restrict__ bb2,
                            float* __restrict__ bias) {
    int h = blockIdx.x;
    int e = threadIdx.x;
    float c0 = coords[h*2 + 0];
    float c1 = coords[h*2 + 1];
    float acc = bb2[e];
    for (int d = 0; d < Dv; ++d) {
        float hd = c0*wb1[d] + c1*wb1[Dv + d] + bb1[d];
        hd = fmaxf(hd, 0.0f);
        acc += hd * wb2[d*DHv + e];
    }
    bias[h*DHv + e] = acc;
}

// ---------------- QKV projection, bf16 MFMA ----------------
__global__ __launch_bounds__(256) void qkv_mfma(const ushort* __restrict__ xbf,
                                                const ushort* __restrict__ wpackT,
                                                const float* __restrict__ bias,
                                                ushort* __restrict__ qbf,
                                                ushort* __restrict__ kbf,
                                                ushort* __restrict__ vtbf) {
    const int mt = blockIdx.x, h = blockIdx.y;
    const int m0 = mt*64;
    const int tid = threadIdx.x;
    const int w = tid >> 6, lane = tid & 63;
    const int g = lane >> 4, r = lane & 15;

    __shared__ char lds[8192 + 24576];
    char* Xs = lds;
    char* Ws = lds + 8192;
    ushort* VtL = (ushort*)lds;

    f32x4 acc[4][3];
    const f32x4 zf = {0.f,0.f,0.f,0.f};
    #pragma unroll
    for (int m = 0; m < 4; ++m)
        #pragma unroll
        for (int n = 0; n < 3; ++n) acc[m][n] = zf;

    const ushort* xb = xbf + (size_t)m0*Dv;
    const ushort* wb = wpackT + (size_t)h*192*Dv;

    for (int kt = 0; kt < Dv; kt += 64) {
        __syncthreads();
        #pragma unroll
        for (int i = 0; i < 2; ++i) {
            int f = tid + i*256;
            int row = f >> 3, c = f & 7;
            *(bf16x8*)(Xs + row*128 + ((c*16) ^ ((row & 7) << 4))) =
                *(const bf16x8*)(xb + (size_t)row*Dv + kt + c*8);
        }
        #pragma unroll
        for (int i = 0; i < 6; ++i) {
            int f = tid + i*256;
            int row = f >> 3, c = f & 7;
            *(bf16x8*)(Ws + row*128 + ((c*16) ^ ((row & 7) << 4))) =
                *(const bf16x8*)(wb + (size_t)row*Dv + kt + c*8);
        }
        __syncthreads();
        #pragma unroll
        for (int kk = 0; kk < 2; ++kk) {
            bf16x8 a[4], bfr[3];
            #pragma unroll
            for (int m = 0; m < 4; ++m) {
                int row = m*16 + r;
                a[m] = *(const bf16x8*)(Xs + row*128 + (((kk*32 + g*8)*2) ^ ((row & 7) << 4)));
            }
            #pragma unroll
            for (int n = 0; n < 3; ++n) {
                int row = (w*3 + n)*16 + r;
                bfr[n] = *(const bf16x8*)(Ws + row*128 + (((kk*32 + g*8)*2) ^ ((row & 7) << 4)));
            }
            #pragma unroll
            for (int m = 0; m < 4; ++m)
                #pragma unroll
                for (int n = 0; n < 3; ++n)
                    acc[m][n] = __builtin_amdgcn_mfma_f32_16x16x32_bf16(a[m], bfr[n], acc[m][n], 0, 0, 0);
        }
    }

    __syncthreads();

    const int bb = m0 >> 11;
    const int s0 = m0 & 2047;
    #pragma unroll
    for (int m = 0; m < 4; ++m) {
        #pragma unroll
        for (int n = 0; n < 3; ++n) {
            int ng = w*3 + n;
            int t = ng >> 2;
            int e = (ng & 3)*16 + r;
            if (t == 0) {
                float bvv = bias[h*DHv + e];
                #pragma unroll
                for (int reg = 0; reg < 4; ++reg) {
                    int ss = s0 + m*16 + g*4 + reg;
                    qbf[(((size_t)bb*H + h)*Sv + ss)*DHv + e] = f2bf((acc[m][n][reg] + bvv)*QSCALE);
                }
            } else if (t == 1) {
                #pragma unroll
                for (int reg = 0; reg < 4; ++reg) {
                    int ss = s0 + m*16 + g*4 + reg;
                    kbf[(((size_t)bb*H + h)*Sv + ss)*DHv + e] = f2bf(acc[m][n][reg]);
                }
            } else {
                #pragma unroll
                for (int reg = 0; reg < 4; ++reg) {
                    int sl = m*16 + g*4 + reg;
                    VtL[e*66 + sl] = f2bf(acc[m][n][reg]);
                }
            }
        }
    }
    __syncthreads();
    #pragma unroll
    for (int i = 0; i < 2; ++i) {
        int f = tid + i*256;
        int dh = f >> 3, sc = f & 7;
        uint u[4];
        #pragma unroll
        for (int j = 0; j < 4; ++j) {
            uint lo = VtL[dh*66 + sc*8 + 2*j];
            uint hi = VtL[dh*66 + sc*8 + 2*j + 1];
            u[j] = lo | (hi << 16);
        }
        *(uint4*)&vtbf[(((size_t)bb*H + h)*DHv + dh)*Sv + s0 + sc*8] = make_uint4(u[0],u[1],u[2],u[3]);
    }
}

// ---------------- MFMA flash attention, swapped-operand softmax ----------------
// Q pre-scaled bf16 [B,H,S,DH]; K bf16 [B,H,S,DH]; V bf16 [B,H,DH,S]; heads bf16 out
__global__ __launch_bounds__(256) void attn_mfma(const ushort* __restrict__ qg,
                                                 const ushort* __restrict__ kg,
                                                 const ushort* __restrict__ vtg,
                                                 ushort* __restrict__ headsbf) {
    const int qt = blockIdx.x, h = blockIdx.y, b = blockIdx.z;
    const int tid = threadIdx.x;
    const int w = tid >> 6, lane = tid & 63;
    const int g = lane >> 4, r = lane & 15;

    __shared__ ushort Ks[4096];     // [kv 64][dh 64] swizzled
    __shared__ ushort Vs[4096];     // [dh 64][kv 64] swizzled
    __shared__ ushort Ps[4][1024];  // per-wave P [q 16][kv 64] swizzled

    const ushort* qb = qg + (((size_t)b*H + h)*Sv + qt*64 + w*16 + r)*DHv;
    const ushort* kb = kg + ((size_t)b*H + h)*Sv*DHv;
    const ushort* vb = vtg + ((size_t)b*H + h)*DHv*Sv;

    bf16x8 qf0 = *(const bf16x8*)(qb + g*8);
    bf16x8 qf1 = *(const bf16x8*)(qb + 32 + g*8);

    float m_run = -1e30f, l_run = 0.f;
    f32x4 o[4];
    const f32x4 zf = {0.f,0.f,0.f,0.f};
    o[0]=zf; o[1]=zf; o[2]=zf; o[3]=zf;

    const int srow = lane >> 3;   // 0..7
    const int scl  = lane & 7;

    for (int jt = 0; jt < Sv/64; ++jt) {
        __syncthreads();
        // stage K [64 kv][64 dh] and V^T [64 dh][64 kv] via global_load_lds,
        // linear LDS dest + inverse-swizzled global source (rule #21)
        #pragma unroll
        for (int is = 0; is < 2; ++is) {
            int row = w*16 + is*8 + srow;
            int kcol = (scl ^ (row & 7)) * 8;
            gll16(kb + (size_t)(jt*64 + row)*DHv + kcol, &Ks[(w*16 + is*8)*64]);
            gll16(vb + (size_t)row*Sv + jt*64 + kcol, &Vs[(w*16 + is*8)*64]);
        }
        asm volatile("s_waitcnt vmcnt(0)" ::: "memory");
        __syncthreads();

        // scores SWAPPED: D[kv][q] = mfma(K, Q) — lane holds q=r, kv = nt*16+g*4+reg
        f32x4 sc[4];
        sc[0]=zf; sc[1]=zf; sc[2]=zf; sc[3]=zf;
        #pragma unroll
        for (int kk = 0; kk < 2; ++kk) {
            bf16x8 qf = kk ? qf1 : qf0;
            #pragma unroll
            for (int nt = 0; nt < 4; ++nt) {
                int kvrow = nt*16 + r;
                bf16x8 kf = *(const bf16x8*)((const char*)Ks + kvrow*128 +
                                             ((kk*64 + g*16) ^ ((kvrow & 7) << 4)));
                sc[nt] = __builtin_amdgcn_mfma_f32_16x16x32_bf16(kf, qf, sc[nt], 0, 0, 0);
            }
        }

        // row-local softmax: 16 values per lane, reduce across g with 2 shuffles
        float pmax = sc[0][0];
        #pragma unroll
        for (int nt = 0; nt < 4; ++nt)
            #pragma unroll
            for (int reg = 0; reg < 4; ++reg)
                pmax = fmaxf(pmax, sc[nt][reg]);
        pmax = fmaxf(pmax, __shfl_xor(pmax, 16));
        pmax = fmaxf(pmax, __shfl_xor(pmax, 32));

        // defer-max (T13): rescale only when needed
        if (__any(pmax > m_run + 8.0f)) {
            float mn = fmaxf(m_run, pmax);
            float corr = __expf(m_run - mn);
            l_run *= corr;
            #pragma unroll
            for (int nt2 = 0; nt2 < 4; ++nt2) {
                o[nt2][0] *= corr; o[nt2][1] *= corr;
                o[nt2][2] *= corr; o[nt2][3] *= corr;
            }
            m_run = mn;
        }

        float lsum = 0.f;
        #pragma unroll
        for (int nt = 0; nt < 4; ++nt) {
            #pragma unroll
            for (int reg = 0; reg < 4; ++reg) {
                float p = __expf(sc[nt][reg] - m_run);
                sc[nt][reg] = p;
                lsum += p;
            }
        }
        lsum += __shfl_xor(lsum, 16);
        lsum += __shfl_xor(lsum, 32);
        l_run += lsum;

        // pack P -> Ps[w] [q=r][kv], b64 writes, chunk-swizzled by q-row
        ushort* pw = Ps[w];
        #pragma unroll
        for (int nt = 0; nt < 4; ++nt) {
            uint u0 = cvtpk(sc[nt][0], sc[nt][1]);
            uint u1 = cvtpk(sc[nt][2], sc[nt][3]);
            int chunk = (2*nt + (g >> 1)) ^ (r & 7);
            *(uint2*)((char*)pw + r*128 + (chunk << 4) + ((g & 1)*8)) = make_uint2(u0, u1);
        }

        // PV SWAPPED: O^T[dh][q] = mfma(V^T, P)
        #pragma unroll
        for (int kk = 0; kk < 2; ++kk) {
            bf16x8 pa = *(const bf16x8*)((const char*)pw + r*128 +
                                         (((kk*4 + g) ^ (r & 7)) << 4));
            #pragma unroll
            for (int nt2 = 0; nt2 < 4; ++nt2) {
                int dh = nt2*16 + r;
                bf16x8 vf = *(const bf16x8*)((const char*)Vs + dh*128 +
                                             ((kk*64 + g*16) ^ ((dh & 7) << 4)));
                o[nt2] = __builtin_amdgcn_mfma_f32_16x16x32_bf16(vf, pa, o[nt2], 0, 0, 0);
            }
        }
    }

    // epilogue: lane holds O^T[dh = nt2*16+g*4+reg][q = r]; store bf16 heads
    float inv = 1.0f / l_run;
    ushort* hp = headsbf + (((size_t)b*H + h)*Sv + qt*64 + w*16 + r)*DHv;
    #pragma unroll
    for (int nt2 = 0; nt2 < 4; ++nt2) {
        uint u0 = cvtpk(o[nt2][0]*inv, o[nt2][1]*inv);
        uint u1 = cvtpk(o[nt2][2]*inv, o[nt2][3]*inv);
        *(uint2*)(hp + nt2*16 + g*4) = make_uint2(u0, u1);
    }
}

// ---------------- msg = relu(heads @ w_mix), bf16 [B,H,S,DH] ----------------
__global__ __launch_bounds__(256) void msg_mfma(const ushort* __restrict__ headsbf,
                                                const ushort* __restrict__ wmixT,
                                                ushort* __restrict__ msgbf) {
    const int st = blockIdx.x, h = blockIdx.y, b = blockIdx.z;
    const int tid = threadIdx.x;
    const int w = tid >> 6, lane = tid & 63;
    const int g = lane >> 4, r = lane & 15;

    __shared__ ushort Hs[4096];
    __shared__ ushort Ws2[4096];

    const ushort* hb = headsbf + ((size_t)((size_t)b*H + h)*Sv + st*64)*DHv;
    const int srow = lane >> 3, scl = lane & 7;
    #pragma unroll
    for (int is = 0; is < 2; ++is) {
        int row = w*16 + is*8 + srow;
        int kcol = (scl ^ (row & 7)) * 8;
        gll16(hb + (size_t)row*DHv + kcol, &Hs[(w*16 + is*8)*64]);
        gll16(wmixT + (size_t)row*DHv + kcol, &Ws2[(w*16 + is*8)*64]);
    }
    asm volatile("s_waitcnt vmcnt(0)" ::: "memory");
    __syncthreads();

    f32x4 acc[4];
    const f32x4 zf = {0.f,0.f,0.f,0.f};
    acc[0]=zf; acc[1]=zf; acc[2]=zf; acc[3]=zf;
    #pragma unroll
    for (int kk = 0; kk < 2; ++kk) {
        int hrow = w*16 + r;
        bf16x8 hf = *(const bf16x8*)((const char*)Hs + hrow*128 +
                                     ((kk*64 + g*16) ^ ((hrow & 7) << 4)));
        #pragma unroll
        for (int nt = 0; nt < 4; ++nt) {
            int erow = nt*16 + r;
            bf16x8 wf = *(const bf16x8*)((const char*)Ws2 + erow*128 +
                                         ((kk*64 + g*16) ^ ((erow & 7) << 4)));
            acc[nt] = __builtin_amdgcn_mfma_f32_16x16x32_bf16(wf, hf, acc[nt], 0, 0, 0);
        }
    }
    // lane holds msg^T[e = nt*16+g*4+reg][s = w*16+r]
    ushort* mp = msgbf + ((size_t)((size_t)b*H + h)*Sv + st*64 + w*16 + r)*DHv;
    #pragma unroll
    for (int nt = 0; nt < 4; ++nt) {
        uint u0 = cvtpk(fmaxf(acc[nt][0], 0.f), fmaxf(acc[nt][1], 0.f));
        uint u1 = cvtpk(fmaxf(acc[nt][2], 0.f), fmaxf(acc[nt][3], 0.f));
        *(uint2*)(mp + nt*16 + g*4) = make_uint2(u0, u1);
    }
}

// ---------------- out projection: [heads|msg] (K=2432) @ woTcat -> out fp32 ----------------
__global__ __launch_bounds__(256) void out_mfma(const ushort* __restrict__ headsbf,
                                                const ushort* __restrict__ msgbf,
                                                const ushort* __restrict__ woTcat,
                                                float* __restrict__ out) {
    const int mt = blockIdx.x, nt2 = blockIdx.y;
    const int m0 = mt*64, n0 = nt2*128;
    const int tid = threadIdx.x;
    const int w = tid >> 6, lane = tid & 63;
    const int g = lane >> 4, r = lane & 15;

    __shared__ char lds[8192 + 16384];
    char* As = lds;
    char* Bs = lds + 8192;

    const int b = m0 >> 11;
    const int s0 = m0 & 2047;

    f32x4 acc[8];
    const f32x4 zf = {0.f,0.f,0.f,0.f};
    #pragma unroll
    for (int n = 0; n < 8; ++n) acc[n] = zf;

    for (int ktile = 0; ktile < KK2/64; ++ktile) {
        const int hh = (ktile < H) ? ktile : ktile - H;
        const ushort* asrc = ((ktile < H) ? headsbf : msgbf) +
                             ((size_t)((size_t)b*H + hh)*Sv + s0)*DHv;
        __syncthreads();
        #pragma unroll
        for (int i = 0; i < 2; ++i) {
            int f = tid + i*256;
            int row = f >> 3, c = f & 7;
            *(bf16x8*)(As + row*128 + ((c*16) ^ ((row & 7) << 4))) =
                *(const bf16x8*)(asrc + (size_t)row*DHv + c*8);
        }
        #pragma unroll
        for (int i = 0; i < 4; ++i) {
            int f = tid + i*256;
            int row = f >> 3, c = f & 7;
            *(bf16x8*)(Bs + row*128 + ((c*16) ^ ((row & 7) << 4))) =
                *(const bf16x8*)(woTcat + (size_t)(n0 + row)*KK2 + ktile*64 + c*8);
        }
        __syncthreads();
        #pragma unroll
        for (int kk = 0; kk < 2; ++kk) {
            int arow = w*16 + r;
            bf16x8 a = *(const bf16x8*)(As + arow*128 + (((kk*32 + g*8)*2) ^ ((arow & 7) << 4)));
            #pragma unroll
            for (int n = 0; n < 8; ++n) {
                int brow = n*16 + r;
                bf16x8 bfr = *(const bf16x8*)(Bs + brow*128 + (((kk*32 + g*8)*2) ^ ((brow & 7) << 4)));
                acc[n] = __builtin_amdgcn_mfma_f32_16x16x32_bf16(a, bfr, acc[n], 0, 0, 0);
            }
        }
    }

    #pragma unroll
    for (int n = 0; n < 8; ++n) {
        #pragma unroll
        for (int reg = 0; reg < 4; ++reg) {
            int grow = m0 + w*16 + g*4 + reg;
            out[(size_t)grow*Dv + n0 + n*16 + r] = acc[n][reg];
        }
    }
}

extern "C" void kernel_launch(void* const* d_in, const int* in_sizes, int n_in,
                              void* d_out, int out_size, void* d_ws, size_t ws_size,
                              hipStream_t stream) {
    const float* x      = (const float*)d_in[0];
    const float* coords = (const float*)d_in[1];
    const float* w_q    = (const float*)d_in[2];
    const float* w_k    = (const float*)d_in[3];
    const float* w_v    = (const float*)d_in[4];
    const float* wb1    = (const float*)d_in[5];
    const float* bb1    = (const float*)d_in[6];
    const float* wb2    = (const float*)d_in[7];
    const float* bb2    = (const float*)d_in[8];
    const float* w_mix  = (const float*)d_in[9];
    const float* adj    = (const float*)d_in[10];
    const float* w_o    = (const float*)d_in[11];

    char* ws = (char*)d_ws;
    const size_t QKV_BYTES = (size_t)Bv*H*Sv*DHv*2;   // 9,961,472
    const size_t XBF_BYTES = (size_t)Bv*Sv*Dv*2;      // 8,388,608
    const size_t WPK_BYTES = (size_t)H*192*Dv*2;      // 7,471,104

    size_t off = 0;
    float*  bias  = (float*)(ws + off);  off += 16384;
    ushort* qbf   = (ushort*)(ws + off); off += QKV_BYTES;
    ushort* kbf   = (ushort*)(ws + off); off += QKV_BYTES;
    ushort* vtbf  = (ushort*)(ws + off); off += QKV_BYTES;
    ushort* hdbf  = (ushort*)(ws + off); off += QKV_BYTES;
    ushort* xbf   = (ushort*)(ws + off);
    ushort* msgbf = xbf;                              // aliases xbf+wpkT (dead after qkv)
    off += XBF_BYTES;
    ushort* wpkT  = (ushort*)(ws + off); off += WPK_BYTES;
    ushort* wmixT = (ushort*)(ws + off); off += 8192;
    ushort* woTc  = (ushort*)(ws + off); off += (size_t)Dv*KK2*2;
    float*  out   = (float*)d_out;

    prep_x<<<(Bv*Sv*Dv)/(256*8), 256, 0, stream>>>(x, xbf);
    prep_w<<<dim3(16, 3, H), 256, 0, stream>>>(w_q, w_k, w_v, wpkT);
    prep_wmix<<<1, 256, 0, stream>>>(w_mix, wmixT);
    prep_wo2<<<dim3(16, H), 256, 0, stream>>>(w_o, adj, woTc);
    bias_kernel<<<H, DHv, 0, stream>>>(coords, wb1, bb1, wb2, bb2, bias);
    qkv_mfma<<<dim3(64, H), 256, 0, stream>>>(xbf, wpkT, bias, qbf, kbf, vtbf);
    attn_mfma<<<dim3(Sv/64, H, Bv), 256, 0, stream>>>(qbf, kbf, vtbf, hdbf);
    msg_mfma<<<dim3(Sv/64, H, Bv), 256, 0, stream>>>(hdbf, wmixT, msgbf);
    out_mfma<<<dim3(64, 8), 256, 0, stream>>>(hdbf, msgbf, woTc, out);
}